// Round 6
// baseline (169.390 us; speedup 1.0000x reference)
//
#include <hip/hip_runtime.h>
#include <hip/hip_bf16.h>

// Y[b,o,hw] = mean_i(W[i,o,:]) . x[b,:,hw] + mean_i(B[i,o])
// B=16, Cin=Cout=64, HW=65536, fp32 in/out.
// R6: race-free reg-staged pipeline (T14 issue-early / write-late):
//   global_load_dwordx4 -> VGPR (prefetch, overlaps compute of prev tile)
//   -> ds_write_b128 -> single 32KB LDS buffer -> R3-verified MFMA recipe
//   -> R2-verified direct stores. No global_load_lds, no dbuf, plain barriers.

#define HW 65536
#define CIN 64
#define COUT 64
#define NB 16
#define NCONV 9
#define TP 128          // positions per tile
#define NT 8            // tiles per block -> 1024 blocks

typedef short s16x8 __attribute__((ext_vector_type(8)));
typedef float f32x4 __attribute__((ext_vector_type(4)));

// float -> bf16 (RNE) raw bits
static __device__ __forceinline__ unsigned short f2bf(float f) {
    unsigned u = __builtin_bit_cast(unsigned, f);
    u = (u + 0x7FFFu + ((u >> 16) & 1u)) >> 16;
    return (unsigned short)u;
}

// ---- pre-kernel: ws[0..8191]B = Wm[o][c] bf16; ws+8192: Bm[64] fp32 ----
__global__ void reduce_wb_kernel(const float* __restrict__ w,
                                 const float* __restrict__ b,
                                 void* __restrict__ wsv) {
    unsigned short* wm = (unsigned short*)wsv;
    float* bm = (float*)((char*)wsv + 8192);
    int tid = blockIdx.x * blockDim.x + threadIdx.x;
    const float inv9 = 1.0f / 9.0f;
    if (tid < COUT * CIN) {
        float s = 0.f;
        #pragma unroll
        for (int i = 0; i < NCONV; ++i) s += w[i * (COUT * CIN) + tid];
        wm[tid] = f2bf(s * inv9);
    } else if (tid < COUT * CIN + COUT) {
        int o = tid - COUT * CIN;
        float s = 0.f;
        #pragma unroll
        for (int i = 0; i < NCONV; ++i) s += b[i * COUT + o];
        bm[o] = s * inv9;
    }
}

// ---- main kernel ----
__global__ __launch_bounds__(256, 3) void conv1x1_regpipe_kernel(
        const float* __restrict__ x,
        const void* __restrict__ wsv,
        float* __restrict__ out) {
    __shared__ float lds[CIN * TP];   // 32 KB single buffer, [c][128]

    const unsigned short* wm = (const unsigned short*)wsv;     // bf16 [64][64]
    const float* bm = (const float*)((const char*)wsv + 8192); // fp32 [64]

    const int tid  = threadIdx.x;
    const int lane = tid & 63;
    const int wave = tid >> 6;    // 0..3
    const int l16  = lane & 15;
    const int lg   = lane >> 4;   // 0..3

    unsigned gbase = blockIdx.x * (unsigned)(TP * NT);  // 1024 positions/block
    unsigned img   = gbase >> 16;                       // TP*NT divides HW
    unsigned p0    = gbase & 65535u;
    const float* __restrict__ xb = x   + (size_t)img * CIN  * HW + p0;
    float* __restrict__       ob = out + (size_t)img * COUT * HW + p0;

    // ---- A fragments (VERIFIED R2/R3 layout):
    // afrag[m][ks][j] = W[o = m*16 + l16][c = ks*32 + lg*8 + j]
    s16x8 afrag[4][2];
    #pragma unroll
    for (int m = 0; m < 4; ++m) {
        #pragma unroll
        for (int ks = 0; ks < 2; ++ks) {
            afrag[m][ks] = *reinterpret_cast<const s16x8*>(
                wm + (m * 16 + l16) * CIN + ks * 32 + lg * 8);
        }
    }
    // bias per D slot: D row (o within 16-block) = lg*4 + r
    f32x4 binit[4];
    #pragma unroll
    for (int m = 0; m < 4; ++m) {
        #pragma unroll
        for (int r = 0; r < 4; ++r) binit[m][r] = bm[m * 16 + lg * 4 + r];
    }

    // ---- register staging: thread owns 8 float4s of the 32KB tile ----
    // slot s: idx = s*256 + tid; c = idx>>5; float col = (idx&31)*4.
    // Global: 1KB contiguous per wave-instr. LDS dst float offset = idx*4
    // (== c*128 + col), b128 writes 2-way bank aliasing = free.
    f32x4 xr[8];
    auto loadtile = [&](int t) {
        #pragma unroll
        for (int s = 0; s < 8; ++s) {
            int idx = s * 256 + tid;
            int c   = idx >> 5;
            int col = (idx & 31) << 2;
            xr[s] = *reinterpret_cast<const f32x4*>(
                xb + (size_t)c * HW + (unsigned)t * (unsigned)TP + (unsigned)col);
        }
    };

    loadtile(0);
    for (int t = 0; t < NT; ++t) {
        __syncthreads();   // all waves done READING lds (previous tile)
        // write-late: deposit tile t (vmcnt drain happens here via register use)
        #pragma unroll
        for (int s = 0; s < 8; ++s) {
            int idx = s * 256 + tid;
            *reinterpret_cast<f32x4*>(&lds[idx * 4]) = xr[s];
        }
        __syncthreads();   // tile t resident for all waves
        if (t + 1 < NT) loadtile(t + 1);   // issue-early: overlaps compute+stores

        // ---- compute (VERIFIED R3 recipe): wave owns 32 positions, 2 n-tiles
        f32x4 acc[2][4];
        #pragma unroll
        for (int nt = 0; nt < 2; ++nt) {
            int pl = wave * 32 + nt * 16 + l16;
            float xf[16];
            #pragma unroll
            for (int ks = 0; ks < 2; ++ks) {
                #pragma unroll
                for (int j = 0; j < 8; ++j)
                    xf[ks * 8 + j] = lds[(ks * 32 + lg * 8 + j) * TP + pl];
            }
            s16x8 bfrag[2];
            #pragma unroll
            for (int ks = 0; ks < 2; ++ks) {
                #pragma unroll
                for (int j = 0; j < 8; ++j)
                    bfrag[ks][j] = (short)f2bf(xf[ks * 8 + j]);
            }
            #pragma unroll
            for (int m = 0; m < 4; ++m) acc[nt][m] = binit[m];
            #pragma unroll
            for (int ks = 0; ks < 2; ++ks) {
                #pragma unroll
                for (int m = 0; m < 4; ++m) {
                    acc[nt][m] = __builtin_amdgcn_mfma_f32_16x16x32_bf16(
                        afrag[m][ks], bfrag[ks], acc[nt][m], 0, 0, 0);
                }
            }
        }

        // ---- direct stores (VERIFIED R2 layout: col=l16=position, row=lg*4+r)
        #pragma unroll
        for (int nt = 0; nt < 2; ++nt) {
            unsigned pos = (unsigned)t * (unsigned)TP
                         + (unsigned)(wave * 32 + nt * 16 + l16);
            #pragma unroll
            for (int m = 0; m < 4; ++m) {
                #pragma unroll
                for (int r = 0; r < 4; ++r) {
                    unsigned o = (unsigned)(m * 16 + lg * 4 + r);
                    ob[(size_t)o * HW + pos] = acc[nt][m][r];
                }
            }
        }
    }
}

extern "C" void kernel_launch(void* const* d_in, const int* in_sizes, int n_in,
                              void* d_out, int out_size, void* d_ws, size_t ws_size,
                              hipStream_t stream) {
    const float* x = (const float*)d_in[0];   // [16][64][256][256]
    const float* w = (const float*)d_in[1];   // [9][64][64][1][1]
    const float* b = (const float*)d_in[2];   // [9][64]
    float* out = (float*)d_out;

    int red_items  = COUT * CIN + COUT;        // 4160
    int red_blocks = (red_items + 255) / 256;  // 17
    reduce_wb_kernel<<<red_blocks, 256, 0, stream>>>(w, b, d_ws);

    unsigned total_blocks = (NB * HW) / (TP * NT);   // 1024
    conv1x1_regpipe_kernel<<<total_blocks, 256, 0, stream>>>(x, d_ws, out);
}

// Round 7
// 91.315 us; speedup vs baseline: 1.8550x; 1.8550x over previous
//
#include <hip/hip_runtime.h>
#include <hip/hip_bf16.h>

// Y[b,o,hw] = mean_i(W[i,o,:]) . x[b,:,hw] + mean_i(B[i,o])
// B=16, Cin=Cout=64, HW=65536, fp32 in/out.
// R7 = R3 structure (8192 single-tile blocks, global_load_lds staging,
// ONE barrier) + 32x32x16 bf16 MFMA so stores are naturally full-line
// coalesced (D col = lane&31 = position) -- no LDS out-transpose.

#define HW 65536
#define CIN 64
#define COUT 64
#define NB 16
#define NCONV 9
#define TP 128   // positions per block

typedef short s16x8 __attribute__((ext_vector_type(8)));
typedef float f32x16 __attribute__((ext_vector_type(16)));

// float -> bf16 (RNE) raw bits
static __device__ __forceinline__ unsigned short f2bf(float f) {
    unsigned u = __builtin_bit_cast(unsigned, f);
    u = (u + 0x7FFFu + ((u >> 16) & 1u)) >> 16;
    return (unsigned short)u;
}

// ---- pre-kernel: ws[0..8191]B = Wm[o][c] bf16; ws+8192: Bm[64] fp32 ----
__global__ void reduce_wb_kernel(const float* __restrict__ w,
                                 const float* __restrict__ b,
                                 void* __restrict__ wsv) {
    unsigned short* wm = (unsigned short*)wsv;
    float* bm = (float*)((char*)wsv + 8192);
    int tid = blockIdx.x * blockDim.x + threadIdx.x;
    const float inv9 = 1.0f / 9.0f;
    if (tid < COUT * CIN) {
        float s = 0.f;
        #pragma unroll
        for (int i = 0; i < NCONV; ++i) s += w[i * (COUT * CIN) + tid];
        wm[tid] = f2bf(s * inv9);
    } else if (tid < COUT * CIN + COUT) {
        int o = tid - COUT * CIN;
        float s = 0.f;
        #pragma unroll
        for (int i = 0; i < NCONV; ++i) s += b[i * COUT + o];
        bm[o] = s * inv9;
    }
}

// ---- main kernel ----
__global__ __launch_bounds__(256, 4) void conv1x1_mfma32_kernel(
        const float* __restrict__ x,
        const void* __restrict__ wsv,
        float* __restrict__ out) {
    __shared__ float lds[CIN * TP];   // 32 KB x-tile, layout [c][128]

    const unsigned short* wm = (const unsigned short*)wsv;     // bf16 [64][64]
    const float* bm = (const float*)((const char*)wsv + 8192); // fp32 [64]

    const int tid  = threadIdx.x;
    const int lane = tid & 63;
    const int wave = tid >> 6;    // 0..3
    const int l31  = lane & 31;
    const int lh   = lane >> 5;   // 0/1

    unsigned pbase = blockIdx.x * (unsigned)TP;
    unsigned img   = pbase >> 16;                 // HW = 2^16, TP | HW
    unsigned p0    = pbase & 65535u;
    const float* __restrict__ xb = x   + (size_t)img * CIN  * HW + p0;
    float* __restrict__       ob = out + (size_t)img * COUT * HW + p0;

    // ---- async stage (VERIFIED R3 pattern): LDS[c][128], c = 2k + lh ----
    {
        #pragma unroll
        for (int i = 0; i < 8; ++i) {
            int k = wave * 8 + i;                       // channel-pair 0..31
            const float* src = xb + ((unsigned)(2 * k + lh)) * (unsigned)HW
                                  + (unsigned)(l31 * 4);
            __builtin_amdgcn_global_load_lds(
                (const __attribute__((address_space(1))) unsigned int*)src,
                (__attribute__((address_space(3))) unsigned int*)&lds[k * 256],
                16, 0, 0);
        }
    }

    // ---- A fragments + bias while loads are in flight ----
    // A frag (analogy of verified 16x16x32 partition, 32 rows x 16 k):
    // afrag[m][kk][j] = W[o = m*32 + l31][c = kk*16 + lh*8 + j]
    s16x8 afrag[2][4];
    #pragma unroll
    for (int m = 0; m < 2; ++m) {
        #pragma unroll
        for (int kk = 0; kk < 4; ++kk) {
            afrag[m][kk] = *reinterpret_cast<const s16x8*>(
                wm + (m * 32 + l31) * CIN + kk * 16 + lh * 8);
        }
    }
    // acc init = bias; D row (within m-block of 32) = (r&3) + 8*(r>>2) + 4*lh
    // (guide-measured m74/m101 layout)
    f32x16 acc[2];
    #pragma unroll
    for (int m = 0; m < 2; ++m) {
        #pragma unroll
        for (int r = 0; r < 16; ++r) {
            acc[m][r] = bm[m * 32 + (r & 3) + 8 * (r >> 2) + 4 * lh];
        }
    }

    __syncthreads();   // x tile resident

    // ---- B fragments: bfrag[kk][j] = X[c = kk*16 + lh*8 + j][pos = wave*32+l31]
    // LDS read: addr = c*128 + pos; lanes 0-31 hit 32 distinct banks, lanes
    // 32-63 alias them 2-way (free per m136).
    const int pl = wave * 32 + l31;
    s16x8 bfrag[4];
    #pragma unroll
    for (int kk = 0; kk < 4; ++kk) {
        float xf[8];
        #pragma unroll
        for (int j = 0; j < 8; ++j)
            xf[j] = lds[(kk * 16 + lh * 8 + j) * TP + pl];
        #pragma unroll
        for (int j = 0; j < 8; ++j)
            bfrag[kk][j] = (short)f2bf(xf[j]);
    }

    #pragma unroll
    for (int kk = 0; kk < 4; ++kk) {
        acc[0] = __builtin_amdgcn_mfma_f32_32x32x16_bf16(
            afrag[0][kk], bfrag[kk], acc[0], 0, 0, 0);
        acc[1] = __builtin_amdgcn_mfma_f32_32x32x16_bf16(
            afrag[1][kk], bfrag[kk], acc[1], 0, 0, 0);
    }

    // ---- direct stores: each (m,r) instr writes 32 consecutive floats per
    // half-wave = one full 128B line. Nontemporal: don't pollute L3.
    float* op = ob + (unsigned)(wave * 32 + l31);
    #pragma unroll
    for (int m = 0; m < 2; ++m) {
        #pragma unroll
        for (int r = 0; r < 16; ++r) {
            int o = m * 32 + (r & 3) + 8 * (r >> 2) + 4 * lh;
            __builtin_nontemporal_store(acc[m][r], op + (size_t)o * HW);
        }
    }
}

extern "C" void kernel_launch(void* const* d_in, const int* in_sizes, int n_in,
                              void* d_out, int out_size, void* d_ws, size_t ws_size,
                              hipStream_t stream) {
    const float* x = (const float*)d_in[0];   // [16][64][256][256]
    const float* w = (const float*)d_in[1];   // [9][64][64][1][1]
    const float* b = (const float*)d_in[2];   // [9][64]
    float* out = (float*)d_out;

    int red_items  = COUT * CIN + COUT;        // 4160
    int red_blocks = (red_items + 255) / 256;  // 17
    reduce_wb_kernel<<<red_blocks, 256, 0, stream>>>(w, b, d_ws);

    unsigned total_blocks = (NB * HW) / TP;    // 8192
    conv1x1_mfma32_kernel<<<total_blocks, 256, 0, stream>>>(x, d_ws, out);
}

// Round 8
// 90.593 us; speedup vs baseline: 1.8698x; 1.0080x over previous
//
#include <hip/hip_runtime.h>
#include <hip/hip_bf16.h>

// Y[b,o,hw] = mean_i(W[i,o,:]) . x[b,:,hw] + mean_i(B[i,o])
// B=16, Cin=Cout=64, HW=65536, fp32 in/out.
// R8 = R7 (8192 single-tile blocks, global_load_lds staging, one barrier,
// 32x32x16 bf16 MFMA, full-line nt-stores) + occupancy 4->5 blocks/CU
// (LDS-exact: 5 x 32KB = 160KB) + W/bias loads hoisted above DMA issue.

#define HW 65536
#define CIN 64
#define COUT 64
#define NB 16
#define NCONV 9
#define TP 128   // positions per block

typedef short s16x8 __attribute__((ext_vector_type(8)));
typedef float f32x16 __attribute__((ext_vector_type(16)));

// float -> bf16 (RNE) raw bits
static __device__ __forceinline__ unsigned short f2bf(float f) {
    unsigned u = __builtin_bit_cast(unsigned, f);
    u = (u + 0x7FFFu + ((u >> 16) & 1u)) >> 16;
    return (unsigned short)u;
}

// ---- pre-kernel: ws[0..8191]B = Wm[o][c] bf16; ws+8192: Bm[64] fp32 ----
__global__ void reduce_wb_kernel(const float* __restrict__ w,
                                 const float* __restrict__ b,
                                 void* __restrict__ wsv) {
    unsigned short* wm = (unsigned short*)wsv;
    float* bm = (float*)((char*)wsv + 8192);
    int tid = blockIdx.x * blockDim.x + threadIdx.x;
    const float inv9 = 1.0f / 9.0f;
    if (tid < COUT * CIN) {
        float s = 0.f;
        #pragma unroll
        for (int i = 0; i < NCONV; ++i) s += w[i * (COUT * CIN) + tid];
        wm[tid] = f2bf(s * inv9);
    } else if (tid < COUT * CIN + COUT) {
        int o = tid - COUT * CIN;
        float s = 0.f;
        #pragma unroll
        for (int i = 0; i < NCONV; ++i) s += b[i * COUT + o];
        bm[o] = s * inv9;
    }
}

// ---- main kernel ----
__global__ __launch_bounds__(256, 5) void conv1x1_mfma32_kernel(
        const float* __restrict__ x,
        const void* __restrict__ wsv,
        float* __restrict__ out) {
    __shared__ float lds[CIN * TP];   // 32 KB x-tile, layout [c][128]

    const unsigned short* wm = (const unsigned short*)wsv;     // bf16 [64][64]
    const float* bm = (const float*)((const char*)wsv + 8192); // fp32 [64]

    const int tid  = threadIdx.x;
    const int lane = tid & 63;
    const int wave = tid >> 6;    // 0..3
    const int l31  = lane & 31;
    const int lh   = lane >> 5;   // 0/1

    unsigned pbase = blockIdx.x * (unsigned)TP;
    unsigned img   = pbase >> 16;                 // HW = 2^16, TP | HW
    unsigned p0    = pbase & 65535u;
    const float* __restrict__ xb = x   + (size_t)img * CIN  * HW + p0;
    float* __restrict__       ob = out + (size_t)img * COUT * HW + p0;

    // ---- A fragments + bias first (their latency overlaps the DMA below) ----
    // afrag[m][kk][j] = W[o = m*32 + l31][c = kk*16 + lh*8 + j]  (R7-verified)
    s16x8 afrag[2][4];
    #pragma unroll
    for (int m = 0; m < 2; ++m) {
        #pragma unroll
        for (int kk = 0; kk < 4; ++kk) {
            afrag[m][kk] = *reinterpret_cast<const s16x8*>(
                wm + (m * 32 + l31) * CIN + kk * 16 + lh * 8);
        }
    }
    // acc init = bias; D row (within m-block of 32) = (r&3) + 8*(r>>2) + 4*lh
    f32x16 acc[2];
    #pragma unroll
    for (int m = 0; m < 2; ++m) {
        #pragma unroll
        for (int r = 0; r < 16; ++r) {
            acc[m][r] = bm[m * 32 + (r & 3) + 8 * (r >> 2) + 4 * lh];
        }
    }

    // ---- async stage (R3/R7-verified pattern): LDS[c][128], c = 2k + lh ----
    {
        #pragma unroll
        for (int i = 0; i < 8; ++i) {
            int k = wave * 8 + i;                       // channel-pair 0..31
            const float* src = xb + ((unsigned)(2 * k + lh)) * (unsigned)HW
                                  + (unsigned)(l31 * 4);
            __builtin_amdgcn_global_load_lds(
                (const __attribute__((address_space(1))) unsigned int*)src,
                (__attribute__((address_space(3))) unsigned int*)&lds[k * 256],
                16, 0, 0);
        }
    }

    __syncthreads();   // x tile resident

    // ---- B fragments: bfrag[kk][j] = X[c = kk*16 + lh*8 + j][pos = wave*32+l31]
    // LDS addr = c*128 + pos; lanes 0-31 distinct banks, 32-63 alias 2-way (free).
    const int pl = wave * 32 + l31;
    s16x8 bfrag[4];
    #pragma unroll
    for (int kk = 0; kk < 4; ++kk) {
        float xf[8];
        #pragma unroll
        for (int j = 0; j < 8; ++j)
            xf[j] = lds[(kk * 16 + lh * 8 + j) * TP + pl];
        #pragma unroll
        for (int j = 0; j < 8; ++j)
            bfrag[kk][j] = (short)f2bf(xf[j]);
    }

    #pragma unroll
    for (int kk = 0; kk < 4; ++kk) {
        acc[0] = __builtin_amdgcn_mfma_f32_32x32x16_bf16(
            afrag[0][kk], bfrag[kk], acc[0], 0, 0, 0);
        acc[1] = __builtin_amdgcn_mfma_f32_32x32x16_bf16(
            afrag[1][kk], bfrag[kk], acc[1], 0, 0, 0);
    }

    // ---- direct stores: each (m,r) instr = 32 consecutive floats per
    // half-wave = one full 128B line. Nontemporal: keep x resident in L3.
    float* op = ob + (unsigned)(wave * 32 + l31);
    #pragma unroll
    for (int m = 0; m < 2; ++m) {
        #pragma unroll
        for (int r = 0; r < 16; ++r) {
            int o = m * 32 + (r & 3) + 8 * (r >> 2) + 4 * lh;
            __builtin_nontemporal_store(acc[m][r], op + (size_t)o * HW);
        }
    }
}

extern "C" void kernel_launch(void* const* d_in, const int* in_sizes, int n_in,
                              void* d_out, int out_size, void* d_ws, size_t ws_size,
                              hipStream_t stream) {
    const float* x = (const float*)d_in[0];   // [16][64][256][256]
    const float* w = (const float*)d_in[1];   // [9][64][64][1][1]
    const float* b = (const float*)d_in[2];   // [9][64]
    float* out = (float*)d_out;

    int red_items  = COUT * CIN + COUT;        // 4160
    int red_blocks = (red_items + 255) / 256;  // 17
    reduce_wb_kernel<<<red_blocks, 256, 0, stream>>>(w, b, d_ws);

    unsigned total_blocks = (NB * HW) / TP;    // 8192
    conv1x1_mfma32_kernel<<<total_blocks, 256, 0, stream>>>(x, d_ws, out);
}